// Round 5
// baseline (140.338 us; speedup 1.0000x reference)
//
#include <hip/hip_runtime.h>

// Problem constants (B,T,C,H) = (8, 2048, 1024, 128)
constexpr int Bz = 8, Tt = 2048, Cc = 1024, Hh = 128;
constexpr int Mrows = Bz * Tt;                 // 16384
constexpr float kScale = 0.08838834764831843f; // 1/sqrt(128)

typedef float f32x4 __attribute__((ext_vector_type(4)));
typedef short s16x8 __attribute__((ext_vector_type(8)));
typedef short s16x4 __attribute__((ext_vector_type(4)));
typedef unsigned short u16;

static __device__ __forceinline__ u16 f2bf(float f) {
    union { float f; unsigned int u; } c; c.f = f;
    unsigned int u = c.u;
    unsigned int r = (u + 0x7fffu + ((u >> 16) & 1u)) >> 16;   // RNE
    return (u16)r;
}

// ---------------------------------------------------------------------------
// Kernel 0: transpose+convert weights.
//   i < 393216 : wt[z][n][k] = bf16(W_z[k][n])   (z: 0=Wq,1=Wk,2=Wv)
//   else       : wpt[n][k]   = bf16(Wp[k][n])    (16384 elems)
// ---------------------------------------------------------------------------
__global__ __launch_bounds__(256) void convw_kernel(
    const float* __restrict__ Wq, const float* __restrict__ Wk,
    const float* __restrict__ Wv, const float* __restrict__ Wp,
    u16* __restrict__ wt, u16* __restrict__ wpt)
{
    int i = blockIdx.x * 256 + threadIdx.x;      // < 409600
    if (i < 393216) {
        int z = i >> 17, r = i & 131071;
        int n = r >> 10, k = r & 1023;
        const float* W = (z == 0) ? Wq : (z == 1) ? Wk : Wv;
        wt[i] = f2bf(W[k * Hh + n]);
    } else {
        int r2 = i - 393216;                     // n*128 + k
        int n = r2 >> 7, k = r2 & 127;
        wpt[r2] = f2bf(Wp[k * Hh + n]);
    }
}

// ---------------------------------------------------------------------------
// Kernel 1: FUSED QKV GEMM — reads x ONCE, computes Q,K,V (+ V^T in place).
// BM=32, BK=64, N=384 (3x128).  grid = 512 blocks, 4 waves.
// A (x tile) staged in LDS; B fragments direct from L2-resident wt.
// Wave w owns cols [w*96, w*96+96) of the 384-wide output.
// z==2 fragments are stored TRANSPOSED into vt[b][h][t] (packed 4-row 8B).
// ---------------------------------------------------------------------------
__global__ __launch_bounds__(256)
__attribute__((amdgpu_waves_per_eu(2, 4)))
void qkv_fused(
    const float* __restrict__ x, const u16* __restrict__ wt,
    u16* __restrict__ qo, u16* __restrict__ ko, u16* __restrict__ vt)
{
    __shared__ __align__(16) u16 as[32 * 64];    // 4 KB

    const int tid  = threadIdx.x;
    const int m0   = blockIdx.x * 32;
    const int lane = tid & 63, wid = tid >> 6;
    const int l15  = lane & 15, l4 = lane >> 4;
    const int bb   = m0 >> 11;                   // batch
    const int t0   = m0 & 2047;                  // seq offset within batch

    f32x4 acc[2][6];
#pragma unroll
    for (int mi = 0; mi < 2; ++mi)
#pragma unroll
        for (int ni = 0; ni < 6; ++ni) {
            f32x4 z4 = {0.f, 0.f, 0.f, 0.f};
            acc[mi][ni] = z4;
        }

    for (int k0 = 0; k0 < Cc; k0 += 64) {
        // stage A: 32x64 fp32 -> bf16 swizzled (512 float4, 2/thread)
#pragma unroll
        for (int u = 0; u < 2; ++u) {
            int idx = tid + u * 256;
            int m = idx >> 4, kf = (idx & 15) * 4;
            float4 xv = *reinterpret_cast<const float4*>(
                &x[(size_t)(m0 + m) * Cc + k0 + kf]);
            s16x4 bv;
            bv[0] = (short)f2bf(xv.x); bv[1] = (short)f2bf(xv.y);
            bv[2] = (short)f2bf(xv.z); bv[3] = (short)f2bf(xv.w);
            *reinterpret_cast<s16x4*>(&as[m * 64 + (kf ^ ((m & 7) << 3))]) = bv;
        }
        __syncthreads();

        // B fragments: 6 col-groups x 2 ks, direct from global (L2)
        s16x8 bfr[6][2];
#pragma unroll
        for (int ni = 0; ni < 6; ++ni) {
            int c = wid * 96 + ni * 16;          // global col base (mult of 16)
            int z = c >> 7, nloc = (c & 127) + l15;
            const u16* wb = wt + (size_t)z * 131072 + (size_t)nloc * 1024 + k0;
#pragma unroll
            for (int ks = 0; ks < 2; ++ks)
                bfr[ni][ks] = *reinterpret_cast<const s16x8*>(&wb[ks * 32 + l4 * 8]);
        }
        // A fragments
        s16x8 af[2][2];
#pragma unroll
        for (int mi = 0; mi < 2; ++mi) {
            int r = mi * 16 + l15;
#pragma unroll
            for (int ks = 0; ks < 2; ++ks)
                af[mi][ks] = *reinterpret_cast<const s16x8*>(
                    &as[r * 64 + ((ks * 32 + l4 * 8) ^ ((r & 7) << 3))]);
        }
#pragma unroll
        for (int mi = 0; mi < 2; ++mi)
#pragma unroll
            for (int ni = 0; ni < 6; ++ni)
#pragma unroll
                for (int ks = 0; ks < 2; ++ks)
                    acc[mi][ni] = __builtin_amdgcn_mfma_f32_16x16x32_bf16(
                        af[mi][ks], bfr[ni][ks], acc[mi][ni], 0, 0, 0);
        __syncthreads();
    }

    // epilogue
#pragma unroll
    for (int mi = 0; mi < 2; ++mi)
#pragma unroll
        for (int ni = 0; ni < 6; ++ni) {
            int c = wid * 96 + ni * 16;
            int z = c >> 7, colz = (c & 127) + l15;
            if (z < 2) {
                u16* outp = (z == 0) ? qo : ko;
#pragma unroll
                for (int r = 0; r < 4; ++r) {
                    int row = m0 + mi * 16 + l4 * 4 + r;
                    outp[(size_t)row * Hh + colz] = f2bf(acc[mi][ni][r]);
                }
            } else {
                // V^T: vt[b][h][t], 4 consecutive t -> one 8B store
                int trow = t0 + mi * 16 + l4 * 4;
                s16x4 pk;
#pragma unroll
                for (int r = 0; r < 4; ++r) pk[r] = (short)f2bf(acc[mi][ni][r]);
                *reinterpret_cast<s16x4*>(
                    &vt[((size_t)bb * Hh + colz) * Tt + trow]) = pk;
            }
        }
}

// ---------------------------------------------------------------------------
// Kernel 2: causal flash attention, in-block KV split, software-pipelined,
// fused output projection.  amdgpu_waves_per_eu(2,3) keeps the K/V prefetch
// pipeline in registers (round-4 failure: scheduler squeezed to 68 VGPR and
// serialized all loads).
// ---------------------------------------------------------------------------
__global__ __launch_bounds__(256)
__attribute__((amdgpu_waves_per_eu(2, 3)))
void attn_kernel(
    const u16* __restrict__ q, const u16* __restrict__ k,
    const u16* __restrict__ vt, const u16* __restrict__ wpt,
    const float* __restrict__ bp, float* __restrict__ O)
{
    __shared__ float Om[4][16][132];     // 33792 B (partial O per wave)
    __shared__ float ml2[4][2][16];      // 512 B
    __shared__ __align__(16) u16 pm[16 * 136];  // 4352 B merged bf16 O

    const int tid = threadIdx.x, lane = tid & 63, wid = tid >> 6;
    const int l15 = lane & 15, l4 = lane >> 4;
    const int bid = blockIdx.x;
    const int b = bid & 7;               // batch -> XCD pinning
    const int p = 127 - (bid >> 3);      // heavy q-tiles first
    const int q0 = p * 16;
    const int ntiles = (p + 2) >> 1;     // ceil(16(p+1)/32)

    const u16* qb = q  + (size_t)b * Tt * Hh;
    const u16* kb = k  + (size_t)b * Tt * Hh;
    const u16* vb = vt + (size_t)b * Hh * Tt;

    // per-wave P scratch aliases Om[wid] (16 x 40 u16, stride 40 pads banks)
    u16* ps = reinterpret_cast<u16*>(&Om[wid][0][0]);

    // Q fragments (A-operand), same 16 rows for all 4 waves
    s16x8 qf[4];
#pragma unroll
    for (int ks = 0; ks < 4; ++ks)
        qf[ks] = *reinterpret_cast<const s16x8*>(
            &qb[(size_t)(q0 + l15) * Hh + ks * 32 + l4 * 8]);

    f32x4 o[8];
#pragma unroll
    for (int nh = 0; nh < 8; ++nh) { f32x4 z4 = {0.f,0.f,0.f,0.f}; o[nh] = z4; }
    float mreg[4], lreg[4];
#pragma unroll
    for (int r = 0; r < 4; ++r) { mreg[r] = -1e30f; lreg[r] = 0.f; }

    int j = wid;
    s16x8 kf[8];                         // current K tile frags (2 nf x 4 ks)
    if (j < ntiles) {
        const int kv0 = j * 32;
#pragma unroll
        for (int nf = 0; nf < 2; ++nf)
#pragma unroll
            for (int ks = 0; ks < 4; ++ks)
                kf[nf * 4 + ks] = *reinterpret_cast<const s16x8*>(
                    &kb[(size_t)(kv0 + nf * 16 + l15) * Hh + ks * 32 + l4 * 8]);
    }

    for (; j < ntiles; j += 4) {
        const int kv0 = j * 32;
        const bool diag = (j == ntiles - 1);

        // issue V loads for this tile (consumed after softmax)
        s16x8 vf[8];
#pragma unroll
        for (int nh = 0; nh < 8; ++nh)
            vf[nh] = *reinterpret_cast<const s16x8*>(
                &vb[(size_t)(nh * 16 + l15) * Tt + kv0 + l4 * 8]);

        // S = Q K^T : 8 MFMAs from resident kf
        f32x4 sacc[2];
#pragma unroll
        for (int nf = 0; nf < 2; ++nf) { f32x4 z4 = {0.f,0.f,0.f,0.f}; sacc[nf] = z4; }
#pragma unroll
        for (int nf = 0; nf < 2; ++nf)
#pragma unroll
            for (int ks = 0; ks < 4; ++ks)
                sacc[nf] = __builtin_amdgcn_mfma_f32_16x16x32_bf16(
                    qf[ks], kf[nf * 4 + ks], sacc[nf], 0, 0, 0);

        // prefetch next K tile into kf (kf dead after QK^T)
        {
            const int jn = (j + 4 < ntiles) ? (j + 4) : j;   // clamp: valid addr
            const int kvn = jn * 32;
#pragma unroll
            for (int nf = 0; nf < 2; ++nf)
#pragma unroll
                for (int ks = 0; ks < 4; ++ks)
                    kf[nf * 4 + ks] = *reinterpret_cast<const s16x8*>(
                        &kb[(size_t)(kvn + nf * 16 + l15) * Hh + ks * 32 + l4 * 8]);
        }

        // scale + causal mask + online softmax (private state)
        float pv2[2][4];
#pragma unroll
        for (int nf = 0; nf < 2; ++nf)
#pragma unroll
            for (int r = 0; r < 4; ++r) {
                float s = sacc[nf][r] * kScale;
                if (diag) {
                    int qq = q0 + l4 * 4 + r;
                    int kk = kv0 + nf * 16 + l15;
                    if (kk > qq) s = -1e30f;
                }
                pv2[nf][r] = s;
            }
#pragma unroll
        for (int r = 0; r < 4; ++r) {
            float mx = fmaxf(pv2[0][r], pv2[1][r]);
            mx = fmaxf(mx, __shfl_xor(mx, 1));
            mx = fmaxf(mx, __shfl_xor(mx, 2));
            mx = fmaxf(mx, __shfl_xor(mx, 4));
            mx = fmaxf(mx, __shfl_xor(mx, 8));
            float mnew = fmaxf(mreg[r], mx);
            float scl = __expf(mreg[r] - mnew);
            mreg[r] = mnew;
            float rs = 0.f;
#pragma unroll
            for (int nf = 0; nf < 2; ++nf) {
                float pp = __expf(pv2[nf][r] - mnew);
                pv2[nf][r] = pp; rs += pp;
            }
            rs += __shfl_xor(rs, 1); rs += __shfl_xor(rs, 2);
            rs += __shfl_xor(rs, 4); rs += __shfl_xor(rs, 8);
            lreg[r] = lreg[r] * scl + rs;
#pragma unroll
            for (int nh = 0; nh < 8; ++nh) o[nh][r] *= scl;
        }

        // P -> per-wave LDS (bf16, stride-40 padded)
#pragma unroll
        for (int nf = 0; nf < 2; ++nf)
#pragma unroll
            for (int r = 0; r < 4; ++r)
                ps[(l4 * 4 + r) * 40 + nf * 16 + l15] = f2bf(pv2[nf][r]);

        // O += P V : 8 MFMAs (vf issued early)
        s16x8 pa = *reinterpret_cast<const s16x8*>(&ps[l15 * 40 + l4 * 8]);
#pragma unroll
        for (int nh = 0; nh < 8; ++nh)
            o[nh] = __builtin_amdgcn_mfma_f32_16x16x32_bf16(pa, vf[nh], o[nh], 0, 0, 0);
    }

    // publish partials
#pragma unroll
    for (int nh = 0; nh < 8; ++nh)
#pragma unroll
        for (int r = 0; r < 4; ++r)
            Om[wid][l4 * 4 + r][nh * 16 + l15] = o[nh][r];
    if (l15 == 0) {
#pragma unroll
        for (int r = 0; r < 4; ++r) {
            ml2[wid][0][l4 * 4 + r] = mreg[r];
            ml2[wid][1][l4 * 4 + r] = lreg[r];
        }
    }
    __syncthreads();

    // merge 4 partials -> normalized bf16 row block pm[16][128] (stride 136)
    {
        const int row = tid >> 4, ch = tid & 15;
        float M = -1e30f;
#pragma unroll
        for (int w = 0; w < 4; ++w) M = fmaxf(M, ml2[w][0][row]);
        float L = 0.f;
        float a[8];
#pragma unroll
        for (int c = 0; c < 8; ++c) a[c] = 0.f;
#pragma unroll
        for (int w = 0; w < 4; ++w) {
            float f = __expf(ml2[w][0][row] - M);
            L += f * ml2[w][1][row];
#pragma unroll
            for (int c = 0; c < 8; ++c) a[c] += f * Om[w][row][ch * 8 + c];
        }
        float inv = 1.f / L;
        union { u16 u[8]; s16x8 v; } pk;
#pragma unroll
        for (int c = 0; c < 8; ++c) pk.u[c] = f2bf(a[c] * inv);
        *reinterpret_cast<s16x8*>(&pm[row * 136 + ch * 8]) = pk.v;
    }
    __syncthreads();

    // fused projection: out[q][n] = pm[q][:] @ WpT[n][:] + bp[n]
    {
        s16x8 af2[4];
#pragma unroll
        for (int ks = 0; ks < 4; ++ks)
            af2[ks] = *reinterpret_cast<const s16x8*>(
                &pm[l15 * 136 + ks * 32 + l4 * 8]);
#pragma unroll
        for (int ni2 = 0; ni2 < 2; ++ni2) {
            const int ncol = (wid * 2 + ni2) * 16 + l15;
            f32x4 pacc = {0.f, 0.f, 0.f, 0.f};
#pragma unroll
            for (int ks = 0; ks < 4; ++ks) {
                s16x8 wf = *reinterpret_cast<const s16x8*>(
                    &wpt[(size_t)ncol * 128 + ks * 32 + l4 * 8]);
                pacc = __builtin_amdgcn_mfma_f32_16x16x32_bf16(af2[ks], wf, pacc, 0, 0, 0);
            }
            float bias = bp[ncol];
#pragma unroll
            for (int r = 0; r < 4; ++r)
                O[((size_t)(b * Tt) + q0 + l4 * 4 + r) * Hh + ncol] = pacc[r] + bias;
        }
    }
}

// ---------------------------------------------------------------------------
extern "C" void kernel_launch(void* const* d_in, const int* in_sizes, int n_in,
                              void* d_out, int out_size, void* d_ws, size_t ws_size,
                              hipStream_t stream) {
    const float* x  = (const float*)d_in[0];
    const float* Wk = (const float*)d_in[1];
    const float* Wq = (const float*)d_in[2];
    const float* Wv = (const float*)d_in[3];
    const float* Wp = (const float*)d_in[4];
    const float* bp = (const float*)d_in[5];
    float* out = (float*)d_out;

    // workspace (u16): wt 393216 | wpt 16384 | qw 2M | kw 2M | vt 2M
    u16* wtb = (u16*)d_ws;
    u16* wpt = wtb + 393216;
    u16* qw  = wpt + 16384;
    u16* kw  = qw + (size_t)Mrows * Hh;
    u16* vtb = kw + (size_t)Mrows * Hh;   // total ~13.4 MB

    convw_kernel<<<1600, 256, 0, stream>>>(Wq, Wk, Wv, Wp, wtb, wpt);
    qkv_fused<<<Mrows / 32, 256, 0, stream>>>(x, wtb, qw, kw, vtb);
    attn_kernel<<<1024, 256, 0, stream>>>(qw, kw, vtb, wpt, bp, out);
}

// Round 6
// 114.772 us; speedup vs baseline: 1.2228x; 1.2228x over previous
//
#include <hip/hip_runtime.h>

// Problem constants (B,T,C,H) = (8, 2048, 1024, 128)
constexpr int Bz = 8, Tt = 2048, Cc = 1024, Hh = 128;
constexpr int Mrows = Bz * Tt;                 // 16384
constexpr float kScale = 0.08838834764831843f; // 1/sqrt(128)

typedef float f32x4 __attribute__((ext_vector_type(4)));
typedef short s16x8 __attribute__((ext_vector_type(8)));
typedef short s16x4 __attribute__((ext_vector_type(4)));
typedef unsigned short u16;

static __device__ __forceinline__ u16 f2bf(float f) {
    union { float f; unsigned int u; } c; c.f = f;
    unsigned int u = c.u;
    unsigned int r = (u + 0x7fffu + ((u >> 16) & 1u)) >> 16;   // RNE
    return (u16)r;
}

// ---------------------------------------------------------------------------
// Kernel 0: transpose+convert weights.
//   i < 393216 : wt[z][n][k] = bf16(W_z[k][n])   (z: 0=Wq,1=Wk,2=Wv)
//   else       : wpt[n][k]   = bf16(Wp[k][n])    (16384 elems)
// ---------------------------------------------------------------------------
__global__ __launch_bounds__(256) void convw_kernel(
    const float* __restrict__ Wq, const float* __restrict__ Wk,
    const float* __restrict__ Wv, const float* __restrict__ Wp,
    u16* __restrict__ wt, u16* __restrict__ wpt)
{
    int i = blockIdx.x * 256 + threadIdx.x;      // < 409600
    if (i < 393216) {
        int z = i >> 17, r = i & 131071;
        int n = r >> 10, k = r & 1023;
        const float* W = (z == 0) ? Wq : (z == 1) ? Wk : Wv;
        wt[i] = f2bf(W[k * Hh + n]);
    } else {
        int r2 = i - 393216;                     // n*128 + k
        int n = r2 >> 7, k = r2 & 127;
        wpt[r2] = f2bf(Wp[k * Hh + n]);
    }
}

// ---------------------------------------------------------------------------
// Kernel 1: FUSED QKV GEMM — reads x ONCE; Q,K + V^T outputs.
// BM=64, BK=64, N=384.  512 threads (8 waves), wave w: cols w*48..w*48+47.
// 24 MFMA : 6 B-loads per wave-iter; B-loads issued BEFORE __syncthreads so
// the barrier's mandatory vmcnt-drain covers their latency.
// ---------------------------------------------------------------------------
__global__ __launch_bounds__(512)
__attribute__((amdgpu_waves_per_eu(2, 4)))
void qkv_fused(
    const float* __restrict__ x, const u16* __restrict__ wt,
    u16* __restrict__ qo, u16* __restrict__ ko, u16* __restrict__ vt)
{
    __shared__ __align__(16) u16 as[64 * 64];    // 8 KB

    const int tid  = threadIdx.x;
    const int m0   = blockIdx.x * 64;
    const int lane = tid & 63, wid = tid >> 6;   // wid 0..7
    const int l15  = lane & 15, l4 = lane >> 4;
    const int bb   = m0 >> 11;                   // batch
    const int t0   = m0 & 2047;                  // seq offset within batch

    f32x4 acc[4][3];
#pragma unroll
    for (int mi = 0; mi < 4; ++mi)
#pragma unroll
        for (int ni = 0; ni < 3; ++ni) {
            f32x4 z4 = {0.f, 0.f, 0.f, 0.f};
            acc[mi][ni] = z4;
        }

    for (int k0 = 0; k0 < Cc; k0 += 64) {
        // stage A: 64x64 fp32 -> bf16 swizzled (1024 float4, 2/thread)
#pragma unroll
        for (int u = 0; u < 2; ++u) {
            int idx = tid + u * 512;
            int m = idx >> 4, kf4 = (idx & 15) * 4;
            float4 xv = *reinterpret_cast<const float4*>(
                &x[(size_t)(m0 + m) * Cc + k0 + kf4]);
            s16x4 bv;
            bv[0] = (short)f2bf(xv.x); bv[1] = (short)f2bf(xv.y);
            bv[2] = (short)f2bf(xv.z); bv[3] = (short)f2bf(xv.w);
            *reinterpret_cast<s16x4*>(&as[m * 64 + (kf4 ^ ((m & 7) << 3))]) = bv;
        }
        // B fragments issued pre-barrier (latency absorbed by barrier drain)
        s16x8 bfr[3][2];
#pragma unroll
        for (int ni = 0; ni < 3; ++ni) {
            int c = wid * 48 + ni * 16;          // 16-col group within one z
            int z = c >> 7, nloc = (c & 127) + l15;
            const u16* wb = wt + (size_t)z * 131072 + (size_t)nloc * 1024 + k0;
#pragma unroll
            for (int ks = 0; ks < 2; ++ks)
                bfr[ni][ks] = *reinterpret_cast<const s16x8*>(&wb[ks * 32 + l4 * 8]);
        }
        __syncthreads();

        s16x8 af[4][2];
#pragma unroll
        for (int mi = 0; mi < 4; ++mi) {
            int r = mi * 16 + l15;
#pragma unroll
            for (int ks = 0; ks < 2; ++ks)
                af[mi][ks] = *reinterpret_cast<const s16x8*>(
                    &as[r * 64 + ((ks * 32 + l4 * 8) ^ ((r & 7) << 3))]);
        }
#pragma unroll
        for (int mi = 0; mi < 4; ++mi)
#pragma unroll
            for (int ni = 0; ni < 3; ++ni)
#pragma unroll
                for (int ks = 0; ks < 2; ++ks)
                    acc[mi][ni] = __builtin_amdgcn_mfma_f32_16x16x32_bf16(
                        af[mi][ks], bfr[ni][ks], acc[mi][ni], 0, 0, 0);
        __syncthreads();
    }

    // epilogue
#pragma unroll
    for (int mi = 0; mi < 4; ++mi)
#pragma unroll
        for (int ni = 0; ni < 3; ++ni) {
            int c = wid * 48 + ni * 16;
            int z = c >> 7, colz = (c & 127) + l15;
            if (z < 2) {
                u16* outp = (z == 0) ? qo : ko;
#pragma unroll
                for (int r = 0; r < 4; ++r) {
                    int row = m0 + mi * 16 + l4 * 4 + r;
                    outp[(size_t)row * Hh + colz] = f2bf(acc[mi][ni][r]);
                }
            } else {
                // V^T: vt[b][h][t], 4 consecutive t -> one 8B store
                int trow = t0 + mi * 16 + l4 * 4;
                s16x4 pk;
#pragma unroll
                for (int r = 0; r < 4; ++r) pk[r] = (short)f2bf(acc[mi][ni][r]);
                *reinterpret_cast<s16x4*>(
                    &vt[((size_t)bb * Hh + colz) * Tt + trow]) = pk;
            }
        }
}

// ---------------------------------------------------------------------------
// Kernel 2: causal flash attention, in-block KV split, swapped-QK^T softmax,
// sched_barrier-pinned register pipeline, fused output projection.
//   S^T = mfma(K, Q): lane owns q-row = l15; softmax = 7 in-lane + 2 shfl.
//   V/K loads pinned at issue points with sched_barrier(0) so they stay
//   hoisted above softmax (round 4/5: compiler sank them -> serial latency).
// ---------------------------------------------------------------------------
__global__ __launch_bounds__(256)
__attribute__((amdgpu_waves_per_eu(2, 2)))
void attn_kernel(
    const u16* __restrict__ q, const u16* __restrict__ k,
    const u16* __restrict__ vt, const u16* __restrict__ wpt,
    const float* __restrict__ bp, float* __restrict__ O)
{
    __shared__ float Om[4][16][132];     // 33792 B (partial O per wave)
    __shared__ float ml2[4][2][16];      // 512 B
    __shared__ __align__(16) u16 pm[16 * 136];  // 4352 B merged bf16 O

    const int tid = threadIdx.x, lane = tid & 63, wid = tid >> 6;
    const int l15 = lane & 15, l4 = lane >> 4;
    const int bid = blockIdx.x;
    const int b = bid & 7;               // batch -> XCD pinning
    const int p = 127 - (bid >> 3);      // heavy q-tiles first
    const int q0 = p * 16;
    const int ntiles = (p + 2) >> 1;     // ceil(16(p+1)/32)

    const u16* qb = q  + (size_t)b * Tt * Hh;
    const u16* kb = k  + (size_t)b * Tt * Hh;
    const u16* vb = vt + (size_t)b * Hh * Tt;

    // per-wave P scratch aliases Om[wid]: P[q][kv], q=row(stride 40), kv=col
    u16* ps = reinterpret_cast<u16*>(&Om[wid][0][0]);

    // Q fragments, row = q0+l15, k = ks*32+l4*8 (used as B-operand of S^T)
    s16x8 qf[4];
#pragma unroll
    for (int ks = 0; ks < 4; ++ks)
        qf[ks] = *reinterpret_cast<const s16x8*>(
            &qb[(size_t)(q0 + l15) * Hh + ks * 32 + l4 * 8]);

    f32x4 o[8];
#pragma unroll
    for (int nh = 0; nh < 8; ++nh) { f32x4 z4 = {0.f,0.f,0.f,0.f}; o[nh] = z4; }
    float mreg = -1e30f, lreg = 0.f;     // per-lane state for q = q0 + l15

    int j = wid;
    s16x8 kf[8];                         // K tile frags (2 nf x 4 ks)
    if (j < ntiles) {
        const int kv0 = j * 32;
#pragma unroll
        for (int nf = 0; nf < 2; ++nf)
#pragma unroll
            for (int ks = 0; ks < 4; ++ks)
                kf[nf * 4 + ks] = *reinterpret_cast<const s16x8*>(
                    &kb[(size_t)(kv0 + nf * 16 + l15) * Hh + ks * 32 + l4 * 8]);
    }

    for (; j < ntiles; j += 4) {
        const int kv0 = j * 32;
        const bool diag = (j == ntiles - 1);

        // issue V loads now; consumed in PV after softmax
        s16x8 vf[8];
#pragma unroll
        for (int nh = 0; nh < 8; ++nh)
            vf[nh] = *reinterpret_cast<const s16x8*>(
                &vb[(size_t)(nh * 16 + l15) * Tt + kv0 + l4 * 8]);
        __builtin_amdgcn_sched_barrier(0);   // pin V issue above QK^T

        // S^T = K Q^T : 8 MFMAs.  C: row=kv_local=l4*4+r (+nf*16), col=q=l15
        f32x4 sacc[2];
#pragma unroll
        for (int nf = 0; nf < 2; ++nf) { f32x4 z4 = {0.f,0.f,0.f,0.f}; sacc[nf] = z4; }
#pragma unroll
        for (int nf = 0; nf < 2; ++nf)
#pragma unroll
            for (int ks = 0; ks < 4; ++ks)
                sacc[nf] = __builtin_amdgcn_mfma_f32_16x16x32_bf16(
                    kf[nf * 4 + ks], qf[ks], sacc[nf], 0, 0, 0);

        // prefetch next K tile (kf dead after QK^T)
        {
            const int jn = (j + 4 < ntiles) ? (j + 4) : j;
            const int kvn = jn * 32;
#pragma unroll
            for (int nf = 0; nf < 2; ++nf)
#pragma unroll
                for (int ks = 0; ks < 4; ++ks)
                    kf[nf * 4 + ks] = *reinterpret_cast<const s16x8*>(
                        &kb[(size_t)(kvn + nf * 16 + l15) * Hh + ks * 32 + l4 * 8]);
        }
        __builtin_amdgcn_sched_barrier(0);   // pin K issue above softmax

        // mask + per-lane softmax (q = q0+l15 fixed per lane)
        float pv2[2][4];
#pragma unroll
        for (int nf = 0; nf < 2; ++nf)
#pragma unroll
            for (int r = 0; r < 4; ++r) {
                float s = sacc[nf][r] * kScale;
                if (diag) {
                    int kvg = kv0 + nf * 16 + l4 * 4 + r;
                    if (kvg > q0 + l15) s = -1e30f;
                }
                pv2[nf][r] = s;
            }
        float mx = fmaxf(fmaxf(fmaxf(pv2[0][0], pv2[0][1]), fmaxf(pv2[0][2], pv2[0][3])),
                         fmaxf(fmaxf(pv2[1][0], pv2[1][1]), fmaxf(pv2[1][2], pv2[1][3])));
        mx = fmaxf(mx, __shfl_xor(mx, 16));
        mx = fmaxf(mx, __shfl_xor(mx, 32));
        float mnew = fmaxf(mreg, mx);
        float scl = __expf(mreg - mnew);
        mreg = mnew;
        float rs = 0.f;
#pragma unroll
        for (int nf = 0; nf < 2; ++nf)
#pragma unroll
            for (int r = 0; r < 4; ++r) {
                float pp = __expf(pv2[nf][r] - mnew);
                pv2[nf][r] = pp; rs += pp;
            }
        rs += __shfl_xor(rs, 16);
        rs += __shfl_xor(rs, 32);
        lreg = lreg * scl + rs;

        // redistribute rescale factor to O's row owners (rows = l4*4+r)
        float sclr[4];
#pragma unroll
        for (int r = 0; r < 4; ++r) sclr[r] = __shfl(scl, l4 * 4 + r);
#pragma unroll
        for (int nh = 0; nh < 8; ++nh)
#pragma unroll
            for (int r = 0; r < 4; ++r) o[nh][r] *= sclr[r];

        // P store (free transpose): ps[q=l15][kv = nf*16 + l4*4 + r]
#pragma unroll
        for (int nf = 0; nf < 2; ++nf)
#pragma unroll
            for (int r = 0; r < 4; ++r)
                ps[l15 * 40 + nf * 16 + l4 * 4 + r] = f2bf(pv2[nf][r]);

        // O += P V : 8 MFMAs (vf issued at iter top)
        s16x8 pa = *reinterpret_cast<const s16x8*>(&ps[l15 * 40 + l4 * 8]);
#pragma unroll
        for (int nh = 0; nh < 8; ++nh)
            o[nh] = __builtin_amdgcn_mfma_f32_16x16x32_bf16(pa, vf[nh], o[nh], 0, 0, 0);
    }

    // publish partials
#pragma unroll
    for (int nh = 0; nh < 8; ++nh)
#pragma unroll
        for (int r = 0; r < 4; ++r)
            Om[wid][l4 * 4 + r][nh * 16 + l15] = o[nh][r];
    if (lane < 16) {
        ml2[wid][0][lane] = mreg;
        ml2[wid][1][lane] = lreg;
    }
    __syncthreads();

    // merge 4 partials -> normalized bf16 row block pm[16][128] (stride 136)
    {
        const int row = tid >> 4, ch = tid & 15;
        float M = -1e30f;
#pragma unroll
        for (int w = 0; w < 4; ++w) M = fmaxf(M, ml2[w][0][row]);
        float L = 0.f;
        float a[8];
#pragma unroll
        for (int c = 0; c < 8; ++c) a[c] = 0.f;
#pragma unroll
        for (int w = 0; w < 4; ++w) {
            float f = __expf(ml2[w][0][row] - M);
            L += f * ml2[w][1][row];
#pragma unroll
            for (int c = 0; c < 8; ++c) a[c] += f * Om[w][row][ch * 8 + c];
        }
        float inv = 1.f / L;
        union { u16 u[8]; s16x8 v; } pk;
#pragma unroll
        for (int c = 0; c < 8; ++c) pk.u[c] = f2bf(a[c] * inv);
        *reinterpret_cast<s16x8*>(&pm[row * 136 + ch * 8]) = pk.v;
    }
    __syncthreads();

    // fused projection: out[q][n] = pm[q][:] @ WpT[n][:] + bp[n]
    {
        s16x8 af2[4];
#pragma unroll
        for (int ks = 0; ks < 4; ++ks)
            af2[ks] = *reinterpret_cast<const s16x8*>(
                &pm[l15 * 136 + ks * 32 + l4 * 8]);
#pragma unroll
        for (int ni2 = 0; ni2 < 2; ++ni2) {
            const int ncol = (wid * 2 + ni2) * 16 + l15;
            f32x4 pacc = {0.f, 0.f, 0.f, 0.f};
#pragma unroll
            for (int ks = 0; ks < 4; ++ks) {
                s16x8 wf = *reinterpret_cast<const s16x8*>(
                    &wpt[(size_t)ncol * 128 + ks * 32 + l4 * 8]);
                pacc = __builtin_amdgcn_mfma_f32_16x16x32_bf16(af2[ks], wf, pacc, 0, 0, 0);
            }
            float bias = bp[ncol];
#pragma unroll
            for (int r = 0; r < 4; ++r)
                O[((size_t)(b * Tt) + q0 + l4 * 4 + r) * Hh + ncol] = pacc[r] + bias;
        }
    }
}

// ---------------------------------------------------------------------------
extern "C" void kernel_launch(void* const* d_in, const int* in_sizes, int n_in,
                              void* d_out, int out_size, void* d_ws, size_t ws_size,
                              hipStream_t stream) {
    const float* x  = (const float*)d_in[0];
    const float* Wk = (const float*)d_in[1];
    const float* Wq = (const float*)d_in[2];
    const float* Wv = (const float*)d_in[3];
    const float* Wp = (const float*)d_in[4];
    const float* bp = (const float*)d_in[5];
    float* out = (float*)d_out;

    // workspace (u16): wt 393216 | wpt 16384 | qw 2M | kw 2M | vt 2M
    u16* wtb = (u16*)d_ws;
    u16* wpt = wtb + 393216;
    u16* qw  = wpt + 16384;
    u16* kw  = qw + (size_t)Mrows * Hh;
    u16* vtb = kw + (size_t)Mrows * Hh;   // total ~13.4 MB

    convw_kernel<<<1600, 256, 0, stream>>>(Wq, Wk, Wv, Wp, wtb, wpt);
    qkv_fused<<<Mrows / 64, 512, 0, stream>>>(x, wtb, qw, kw, vtb);
    attn_kernel<<<1024, 256, 0, stream>>>(qw, kw, vtb, wpt, bp, out);
}

// Round 9
// 111.444 us; speedup vs baseline: 1.2593x; 1.0299x over previous
//
#include <hip/hip_runtime.h>

// Problem constants (B,T,C,H) = (8, 2048, 1024, 128)
constexpr int Bz = 8, Tt = 2048, Cc = 1024, Hh = 128;
constexpr int Mrows = Bz * Tt;                 // 16384
constexpr float kScale = 0.08838834764831843f; // 1/sqrt(128)

typedef float f32x4 __attribute__((ext_vector_type(4)));
typedef short s16x8 __attribute__((ext_vector_type(8)));
typedef short s16x4 __attribute__((ext_vector_type(4)));
typedef unsigned short u16;

static __device__ __forceinline__ u16 f2bf(float f) {
    union { float f; unsigned int u; } c; c.f = f;
    unsigned int u = c.u;
    unsigned int r = (u + 0x7fffu + ((u >> 16) & 1u)) >> 16;   // RNE
    return (u16)r;
}

// ---------------------------------------------------------------------------
// Kernel 0: transpose+convert weights.
//   i < 393216 : wt[z][n][k] = bf16(W_z[k][n])   (z: 0=Wq,1=Wk,2=Wv)
//   else       : wpt[n][k]   = bf16(Wp[k][n])    (16384 elems)
// ---------------------------------------------------------------------------
__global__ __launch_bounds__(256) void convw_kernel(
    const float* __restrict__ Wq, const float* __restrict__ Wk,
    const float* __restrict__ Wv, const float* __restrict__ Wp,
    u16* __restrict__ wt, u16* __restrict__ wpt)
{
    int i = blockIdx.x * 256 + threadIdx.x;      // < 409600
    if (i < 393216) {
        int z = i >> 17, r = i & 131071;
        int n = r >> 10, k = r & 1023;
        const float* W = (z == 0) ? Wq : (z == 1) ? Wk : Wv;
        wt[i] = f2bf(W[k * Hh + n]);
    } else {
        int r2 = i - 393216;                     // n*128 + k
        int n = r2 >> 7, k = r2 & 127;
        wpt[r2] = f2bf(Wp[k * Hh + n]);
    }
}

// ---------------------------------------------------------------------------
// Kernel 1: FUSED QKV GEMM — reads x ONCE; Q,K + V^T outputs.
// (verbatim round-6 version: passed at ~35 µs)
// ---------------------------------------------------------------------------
__global__ __launch_bounds__(512)
__attribute__((amdgpu_waves_per_eu(2, 4)))
void qkv_fused(
    const float* __restrict__ x, const u16* __restrict__ wt,
    u16* __restrict__ qo, u16* __restrict__ ko, u16* __restrict__ vt)
{
    __shared__ __align__(16) u16 as[64 * 64];    // 8 KB

    const int tid  = threadIdx.x;
    const int m0   = blockIdx.x * 64;
    const int lane = tid & 63, wid = tid >> 6;   // wid 0..7
    const int l15  = lane & 15, l4 = lane >> 4;
    const int bb   = m0 >> 11;                   // batch
    const int t0   = m0 & 2047;                  // seq offset within batch

    f32x4 acc[4][3];
#pragma unroll
    for (int mi = 0; mi < 4; ++mi)
#pragma unroll
        for (int ni = 0; ni < 3; ++ni) {
            f32x4 z4 = {0.f, 0.f, 0.f, 0.f};
            acc[mi][ni] = z4;
        }

    for (int k0 = 0; k0 < Cc; k0 += 64) {
        // stage A: 64x64 fp32 -> bf16 swizzled (1024 float4, 2/thread)
#pragma unroll
        for (int u = 0; u < 2; ++u) {
            int idx = tid + u * 512;
            int m = idx >> 4, kf4 = (idx & 15) * 4;
            float4 xv = *reinterpret_cast<const float4*>(
                &x[(size_t)(m0 + m) * Cc + k0 + kf4]);
            s16x4 bv;
            bv[0] = (short)f2bf(xv.x); bv[1] = (short)f2bf(xv.y);
            bv[2] = (short)f2bf(xv.z); bv[3] = (short)f2bf(xv.w);
            *reinterpret_cast<s16x4*>(&as[m * 64 + (kf4 ^ ((m & 7) << 3))]) = bv;
        }
        // B fragments issued pre-barrier (latency absorbed by barrier drain)
        s16x8 bfr[3][2];
#pragma unroll
        for (int ni = 0; ni < 3; ++ni) {
            int c = wid * 48 + ni * 16;          // 16-col group within one z
            int z = c >> 7, nloc = (c & 127) + l15;
            const u16* wb = wt + (size_t)z * 131072 + (size_t)nloc * 1024 + k0;
#pragma unroll
            for (int ks = 0; ks < 2; ++ks)
                bfr[ni][ks] = *reinterpret_cast<const s16x8*>(&wb[ks * 32 + l4 * 8]);
        }
        __syncthreads();

        s16x8 af[4][2];
#pragma unroll
        for (int mi = 0; mi < 4; ++mi) {
            int r = mi * 16 + l15;
#pragma unroll
            for (int ks = 0; ks < 2; ++ks)
                af[mi][ks] = *reinterpret_cast<const s16x8*>(
                    &as[r * 64 + ((ks * 32 + l4 * 8) ^ ((r & 7) << 3))]);
        }
#pragma unroll
        for (int mi = 0; mi < 4; ++mi)
#pragma unroll
            for (int ni = 0; ni < 3; ++ni)
#pragma unroll
                for (int ks = 0; ks < 2; ++ks)
                    acc[mi][ni] = __builtin_amdgcn_mfma_f32_16x16x32_bf16(
                        af[mi][ks], bfr[ni][ks], acc[mi][ni], 0, 0, 0);
        __syncthreads();
    }

    // epilogue
#pragma unroll
    for (int mi = 0; mi < 4; ++mi)
#pragma unroll
        for (int ni = 0; ni < 3; ++ni) {
            int c = wid * 48 + ni * 16;
            int z = c >> 7, colz = (c & 127) + l15;
            if (z < 2) {
                u16* outp = (z == 0) ? qo : ko;
#pragma unroll
                for (int r = 0; r < 4; ++r) {
                    int row = m0 + mi * 16 + l4 * 4 + r;
                    outp[(size_t)row * Hh + colz] = f2bf(acc[mi][ni][r]);
                }
            } else {
                int trow = t0 + mi * 16 + l4 * 4;
                s16x4 pk;
#pragma unroll
                for (int r = 0; r < 4; ++r) pk[r] = (short)f2bf(acc[mi][ni][r]);
                *reinterpret_cast<s16x4*>(
                    &vt[((size_t)bb * Hh + colz) * Tt + trow]) = pk;
            }
        }
}

// ---------------------------------------------------------------------------
// Kernel 2: classic-flash causal attention, cooperative LDS staging, fused
// output projection.  Block = 64 q-rows (4 waves x 16, DISTINCT rows), one
// shared kv tile of 64 per iter staged by all 256 threads (plain loads +
// ds_write + __syncthreads; compiler-managed waits — no inline asm).
// Per-wave-complete online softmax; no merge.  grid = 256 (1 block/CU),
// wall time set by heaviest block (qt=31: 32 iters).
// ---------------------------------------------------------------------------
__global__ __launch_bounds__(256, 1)
void attn_kernel(
    const u16* __restrict__ q, const u16* __restrict__ k,
    const u16* __restrict__ vt, const u16* __restrict__ wpt,
    const float* __restrict__ bp, float* __restrict__ O)
{
    __shared__ __align__(16) u16 ksl[64 * 128];   // 16 KB; aliased as pm later
    __shared__ __align__(16) u16 vsl[128 * 64];   // 16 KB
    __shared__ __align__(16) u16 psl[4][16 * 80]; // 10 KB  P scratch per wave

    const int tid = threadIdx.x, lane = tid & 63, wid = tid >> 6;
    const int l15 = lane & 15, l4 = lane >> 4;
    const int bid = blockIdx.x;
    const int b  = bid & 7;              // batch -> XCD pinning
    const int qt = 31 - (bid >> 3);      // heavy q-tiles first
    const int q0 = qt * 64;

    const u16* qb = q  + (size_t)b * Tt * Hh;
    const u16* kb = k  + (size_t)b * Tt * Hh;
    const u16* vb = vt + (size_t)b * Hh * Tt;

    // Q fragments (B-operand of S^T): wave's q-row = q0 + wid*16 + l15
    const int qrow = q0 + wid * 16 + l15;
    s16x8 qf[4];
#pragma unroll
    for (int ks = 0; ks < 4; ++ks)
        qf[ks] = *reinterpret_cast<const s16x8*>(
            &qb[(size_t)qrow * Hh + ks * 32 + l4 * 8]);

    f32x4 o[8];
#pragma unroll
    for (int nh = 0; nh < 8; ++nh) { f32x4 z4 = {0.f,0.f,0.f,0.f}; o[nh] = z4; }
    float mreg = -1e30f, lreg = 0.f;     // per-lane state for q-row (l15)

    // staging assignments
    const int kr_s  = tid >> 2, kc_s = (tid & 3) * 4;   // K: row, 4 granules
    const int vh_s  = tid >> 1, vc_s = (tid & 1) * 4;   // V: row, 4 granules
    u16* ps = &psl[wid][0];

    for (int j = 0; j <= qt; ++j) {
        const int kv0 = j * 64;

        // ---- cooperative staging (granule = 8 u16 = 16B; XOR-swizzled) ----
#pragma unroll
        for (int i = 0; i < 4; ++i) {
            s16x8 tk = *reinterpret_cast<const s16x8*>(
                &kb[(size_t)(kv0 + kr_s) * Hh + (kc_s + i) * 8]);
            *reinterpret_cast<s16x8*>(
                &ksl[kr_s * 128 + (((kc_s + i) * 8) ^ ((kr_s & 7) << 3))]) = tk;
        }
#pragma unroll
        for (int i = 0; i < 4; ++i) {
            s16x8 tv = *reinterpret_cast<const s16x8*>(
                &vb[(size_t)vh_s * Tt + kv0 + (vc_s + i) * 8]);
            *reinterpret_cast<s16x8*>(
                &vsl[vh_s * 64 + (((vc_s + i) * 8) ^ ((vh_s & 7) << 3))]) = tv;
        }
        __syncthreads();

        // ---- S^T = K Q^T : 16 MFMAs (C: row=kv_local, col=q=l15) ----
        f32x4 sacc[4];
#pragma unroll
        for (int nf = 0; nf < 4; ++nf) { f32x4 z4 = {0.f,0.f,0.f,0.f}; sacc[nf] = z4; }
#pragma unroll
        for (int nf = 0; nf < 4; ++nf) {
            const int kr = nf * 16 + l15;
#pragma unroll
            for (int ks = 0; ks < 4; ++ks) {
                s16x8 kfrag = *reinterpret_cast<const s16x8*>(
                    &ksl[kr * 128 + ((ks * 32 + l4 * 8) ^ ((kr & 7) << 3))]);
                sacc[nf] = __builtin_amdgcn_mfma_f32_16x16x32_bf16(
                    kfrag, qf[ks], sacc[nf], 0, 0, 0);
            }
        }

        // ---- mask + per-lane online softmax (q fixed per lane) ----
        const bool diag = (j == qt);
        float pv2[4][4];
#pragma unroll
        for (int nf = 0; nf < 4; ++nf)
#pragma unroll
            for (int r = 0; r < 4; ++r) {
                float s = sacc[nf][r] * kScale;
                if (diag) {
                    int kvg = kv0 + nf * 16 + l4 * 4 + r;
                    if (kvg > qrow) s = -1e30f;
                }
                pv2[nf][r] = s;
            }
        float mx = -1e30f;
#pragma unroll
        for (int nf = 0; nf < 4; ++nf)
            mx = fmaxf(mx, fmaxf(fmaxf(pv2[nf][0], pv2[nf][1]),
                                 fmaxf(pv2[nf][2], pv2[nf][3])));
        mx = fmaxf(mx, __shfl_xor(mx, 16));
        mx = fmaxf(mx, __shfl_xor(mx, 32));
        const float mold = mreg;
        const float mnew = fmaxf(mold, mx);
        const float scl = __expf(mold - mnew);
        mreg = mnew;
        float rs = 0.f;
#pragma unroll
        for (int nf = 0; nf < 4; ++nf)
#pragma unroll
            for (int r = 0; r < 4; ++r) {
                float pp = __expf(pv2[nf][r] - mnew);
                pv2[nf][r] = pp; rs += pp;
            }
        rs += __shfl_xor(rs, 16);
        rs += __shfl_xor(rs, 32);
        lreg = lreg * scl + rs;

        if (!__all(mold == mnew)) {      // O-rescale only when max moved
            float sclr[4];
#pragma unroll
            for (int r = 0; r < 4; ++r) sclr[r] = __shfl(scl, l4 * 4 + r);
#pragma unroll
            for (int nh = 0; nh < 8; ++nh)
#pragma unroll
                for (int r = 0; r < 4; ++r) o[nh][r] *= sclr[r];
        }

        // ---- P -> per-wave LDS (row q=l15, stride 80 u16 = 160B) ----
#pragma unroll
        for (int nf = 0; nf < 4; ++nf) {
            s16x4 pk4;
#pragma unroll
            for (int r = 0; r < 4; ++r) pk4[r] = (short)f2bf(pv2[nf][r]);
            *reinterpret_cast<s16x4*>(&ps[l15 * 80 + nf * 16 + l4 * 4]) = pk4;
        }
        s16x8 pa[2];
#pragma unroll
        for (int ks2 = 0; ks2 < 2; ++ks2)
            pa[ks2] = *reinterpret_cast<const s16x8*>(
                &ps[l15 * 80 + ks2 * 32 + l4 * 8]);

        // ---- O += P V : 16 MFMAs ----
#pragma unroll
        for (int nh = 0; nh < 8; ++nh) {
            const int hr = nh * 16 + l15;
#pragma unroll
            for (int ks2 = 0; ks2 < 2; ++ks2) {
                s16x8 vfrag = *reinterpret_cast<const s16x8*>(
                    &vsl[hr * 64 + ((ks2 * 32 + l4 * 8) ^ ((hr & 7) << 3))]);
                o[nh] = __builtin_amdgcn_mfma_f32_16x16x32_bf16(
                    pa[ks2], vfrag, o[nh], 0, 0, 0);
            }
        }
        __syncthreads();                 // tile consumed; safe to restage
    }

    // ---- epilogue: normalize -> bf16 pm (aliases ksl) -> projection ----
    u16* pm = ksl;                       // 64 rows x 128 cols, granule-swizzled
    {
        float invr[4];
#pragma unroll
        for (int r = 0; r < 4; ++r) invr[r] = 1.f / __shfl(lreg, l4 * 4 + r);
#pragma unroll
        for (int nh = 0; nh < 8; ++nh)
#pragma unroll
            for (int r = 0; r < 4; ++r) {
                int row = wid * 16 + l4 * 4 + r;
                int col = nh * 16 + l15;
                pm[row * 128 + (((col & ~7) ^ ((row & 7) << 3)) + (col & 7))] =
                    f2bf(o[nh][r] * invr[r]);
            }
    }
    // wave reads only its own rows -> intra-wave LDS ordering suffices,
    // but waves alias ksl across the whole block; all waves already passed
    // the final loop barrier, so no cross-wave hazard on reuse.

    {
        const int row2 = wid * 16 + l15;
        s16x8 af2[4];
#pragma unroll
        for (int ks = 0; ks < 4; ++ks)
            af2[ks] = *reinterpret_cast<const s16x8*>(
                &pm[row2 * 128 + ((ks * 32 + l4 * 8) ^ ((row2 & 7) << 3))]);
#pragma unroll
        for (int ng = 0; ng < 8; ++ng) {
            const int ncol = ng * 16 + l15;
            f32x4 pacc = {0.f, 0.f, 0.f, 0.f};
#pragma unroll
            for (int ks = 0; ks < 4; ++ks) {
                s16x8 wf = *reinterpret_cast<const s16x8*>(
                    &wpt[(size_t)ncol * 128 + ks * 32 + l4 * 8]);
                pacc = __builtin_amdgcn_mfma_f32_16x16x32_bf16(
                    af2[ks], wf, pacc, 0, 0, 0);
            }
            float bias = bp[ncol];
#pragma unroll
            for (int r = 0; r < 4; ++r)
                O[((size_t)(b * Tt) + q0 + wid * 16 + l4 * 4 + r) * Hh + ncol] =
                    pacc[r] + bias;
        }
    }
}

// ---------------------------------------------------------------------------
extern "C" void kernel_launch(void* const* d_in, const int* in_sizes, int n_in,
                              void* d_out, int out_size, void* d_ws, size_t ws_size,
                              hipStream_t stream) {
    const float* x  = (const float*)d_in[0];
    const float* Wk = (const float*)d_in[1];
    const float* Wq = (const float*)d_in[2];
    const float* Wv = (const float*)d_in[3];
    const float* Wp = (const float*)d_in[4];
    const float* bp = (const float*)d_in[5];
    float* out = (float*)d_out;

    // workspace (u16): wt 393216 | wpt 16384 | qw 2M | kw 2M | vt 2M
    u16* wtb = (u16*)d_ws;
    u16* wpt = wtb + 393216;
    u16* qw  = wpt + 16384;
    u16* kw  = qw + (size_t)Mrows * Hh;
    u16* vtb = kw + (size_t)Mrows * Hh;   // total ~13.4 MB

    convw_kernel<<<1600, 256, 0, stream>>>(Wq, Wk, Wv, Wp, wtb, wpt);
    qkv_fused<<<Mrows / 64, 512, 0, stream>>>(x, wtb, qw, kw, vtb);
    attn_kernel<<<256, 256, 0, stream>>>(qw, kw, vtb, wpt, bp, out);
}

// Round 10
// 96.866 us; speedup vs baseline: 1.4488x; 1.1505x over previous
//
#include <hip/hip_runtime.h>

// Problem constants (B,T,C,H) = (8, 2048, 1024, 128)
constexpr int Bz = 8, Tt = 2048, Cc = 1024, Hh = 128;
constexpr int Mrows = Bz * Tt;                 // 16384
constexpr float kScale = 0.08838834764831843f; // 1/sqrt(128)

typedef float f32x4 __attribute__((ext_vector_type(4)));
typedef short s16x8 __attribute__((ext_vector_type(8)));
typedef short s16x4 __attribute__((ext_vector_type(4)));
typedef unsigned short u16;

static __device__ __forceinline__ u16 f2bf(float f) {
    union { float f; unsigned int u; } c; c.f = f;
    unsigned int u = c.u;
    unsigned int r = (u + 0x7fffu + ((u >> 16) & 1u)) >> 16;   // RNE
    return (u16)r;
}

// ---------------------------------------------------------------------------
// Kernel 0: transpose+convert weights.
//   i < 393216 : wt[z][n][k] = bf16(W_z[k][n])   (z: 0=Wq,1=Wk,2=Wv)
//   else       : wpt[n][k]   = bf16(Wp[k][n])    (16384 elems)
// ---------------------------------------------------------------------------
__global__ __launch_bounds__(256) void convw_kernel(
    const float* __restrict__ Wq, const float* __restrict__ Wk,
    const float* __restrict__ Wv, const float* __restrict__ Wp,
    u16* __restrict__ wt, u16* __restrict__ wpt)
{
    int i = blockIdx.x * 256 + threadIdx.x;      // < 409600
    if (i < 393216) {
        int z = i >> 17, r = i & 131071;
        int n = r >> 10, k = r & 1023;
        const float* W = (z == 0) ? Wq : (z == 1) ? Wk : Wv;
        wt[i] = f2bf(W[k * Hh + n]);
    } else {
        int r2 = i - 393216;                     // n*128 + k
        int n = r2 >> 7, k = r2 & 127;
        wpt[r2] = f2bf(Wp[k * Hh + n]);
    }
}

// ---------------------------------------------------------------------------
// Kernel 1: FUSED QKV GEMM — reads x ONCE; Q,K + V^T outputs.
// (verbatim round-6/9 version: passing)
// ---------------------------------------------------------------------------
__global__ __launch_bounds__(512)
__attribute__((amdgpu_waves_per_eu(2, 4)))
void qkv_fused(
    const float* __restrict__ x, const u16* __restrict__ wt,
    u16* __restrict__ qo, u16* __restrict__ ko, u16* __restrict__ vt)
{
    __shared__ __align__(16) u16 as[64 * 64];    // 8 KB

    const int tid  = threadIdx.x;
    const int m0   = blockIdx.x * 64;
    const int lane = tid & 63, wid = tid >> 6;   // wid 0..7
    const int l15  = lane & 15, l4 = lane >> 4;
    const int bb   = m0 >> 11;                   // batch
    const int t0   = m0 & 2047;                  // seq offset within batch

    f32x4 acc[4][3];
#pragma unroll
    for (int mi = 0; mi < 4; ++mi)
#pragma unroll
        for (int ni = 0; ni < 3; ++ni) {
            f32x4 z4 = {0.f, 0.f, 0.f, 0.f};
            acc[mi][ni] = z4;
        }

    for (int k0 = 0; k0 < Cc; k0 += 64) {
        // stage A: 64x64 fp32 -> bf16 swizzled (1024 float4, 2/thread)
#pragma unroll
        for (int u = 0; u < 2; ++u) {
            int idx = tid + u * 512;
            int m = idx >> 4, kf4 = (idx & 15) * 4;
            float4 xv = *reinterpret_cast<const float4*>(
                &x[(size_t)(m0 + m) * Cc + k0 + kf4]);
            s16x4 bv;
            bv[0] = (short)f2bf(xv.x); bv[1] = (short)f2bf(xv.y);
            bv[2] = (short)f2bf(xv.z); bv[3] = (short)f2bf(xv.w);
            *reinterpret_cast<s16x4*>(&as[m * 64 + (kf4 ^ ((m & 7) << 3))]) = bv;
        }
        // B fragments issued pre-barrier (latency absorbed by barrier drain)
        s16x8 bfr[3][2];
#pragma unroll
        for (int ni = 0; ni < 3; ++ni) {
            int c = wid * 48 + ni * 16;          // 16-col group within one z
            int z = c >> 7, nloc = (c & 127) + l15;
            const u16* wb = wt + (size_t)z * 131072 + (size_t)nloc * 1024 + k0;
#pragma unroll
            for (int ks = 0; ks < 2; ++ks)
                bfr[ni][ks] = *reinterpret_cast<const s16x8*>(&wb[ks * 32 + l4 * 8]);
        }
        __syncthreads();

        s16x8 af[4][2];
#pragma unroll
        for (int mi = 0; mi < 4; ++mi) {
            int r = mi * 16 + l15;
#pragma unroll
            for (int ks = 0; ks < 2; ++ks)
                af[mi][ks] = *reinterpret_cast<const s16x8*>(
                    &as[r * 64 + ((ks * 32 + l4 * 8) ^ ((r & 7) << 3))]);
        }
#pragma unroll
        for (int mi = 0; mi < 4; ++mi)
#pragma unroll
            for (int ni = 0; ni < 3; ++ni)
#pragma unroll
                for (int ks = 0; ks < 2; ++ks)
                    acc[mi][ni] = __builtin_amdgcn_mfma_f32_16x16x32_bf16(
                        af[mi][ks], bfr[ni][ks], acc[mi][ni], 0, 0, 0);
        __syncthreads();
    }

    // epilogue
#pragma unroll
    for (int mi = 0; mi < 4; ++mi)
#pragma unroll
        for (int ni = 0; ni < 3; ++ni) {
            int c = wid * 48 + ni * 16;
            int z = c >> 7, colz = (c & 127) + l15;
            if (z < 2) {
                u16* outp = (z == 0) ? qo : ko;
#pragma unroll
                for (int r = 0; r < 4; ++r) {
                    int row = m0 + mi * 16 + l4 * 4 + r;
                    outp[(size_t)row * Hh + colz] = f2bf(acc[mi][ni][r]);
                }
            } else {
                int trow = t0 + mi * 16 + l4 * 4;
                s16x4 pk;
#pragma unroll
                for (int r = 0; r < 4; ++r) pk[r] = (short)f2bf(acc[mi][ni][r]);
                *reinterpret_cast<s16x4*>(
                    &vt[((size_t)bb * Hh + colz) * Tt + trow]) = pk;
            }
        }
}

// ---------------------------------------------------------------------------
// Kernel 2: classic-flash causal attention, q-tile 32, kv-half split.
// grid = 512 (2 blocks/CU, 2 waves/SIMD).  Block = 4 waves: wave (wq,half)
// owns q-rows wq*16..+15 and kv-half `half` of each staged kv-64 tile
// (8 QK^T + 8 PV MFMAs / wave / iter).  End merge of 2 partials per
// row-group via LDS.  LDS phases aliased in one 43 KB arena.
// ---------------------------------------------------------------------------
__global__ __launch_bounds__(256, 2)
void attn_kernel(
    const u16* __restrict__ q, const u16* __restrict__ k,
    const u16* __restrict__ vt, const u16* __restrict__ wpt,
    const float* __restrict__ bp, float* __restrict__ O)
{
    __shared__ __align__(16) char arena[43008];
    // loop phase:
    u16* ksl = reinterpret_cast<u16*>(arena);              // 64x128 u16, 16 KB
    u16* vsl = reinterpret_cast<u16*>(arena + 16384);      // 128x64 u16, 16 KB
    u16* psl = reinterpret_cast<u16*>(arena + 32768);      // 4 x 16x80 u16, 10 KB
    // epilogue phase (after loop-final barrier; aliases the above):
    float* Om  = reinterpret_cast<float*>(arena);          // [4][16][132] f32
    float* ml2 = reinterpret_cast<float*>(arena + 33792);  // [4][2][16] f32
    u16*   pm  = reinterpret_cast<u16*>(arena + 34304);    // [32][136] u16

    const int tid = threadIdx.x, lane = tid & 63, wid = tid >> 6;
    const int l15 = lane & 15, l4 = lane >> 4;
    const int wq = wid >> 1, half = wid & 1;
    const int bid = blockIdx.x;
    const int b  = bid & 7;              // batch -> XCD pinning
    const int qt = 63 - (bid >> 3);      // heavy q-tiles first
    const int q0 = qt * 32;
    const int ntiles = (qt + 2) >> 1;    // ceil((q0+32)/64)

    const u16* qb = q  + (size_t)b * Tt * Hh;
    const u16* kb = k  + (size_t)b * Tt * Hh;
    const u16* vb = vt + (size_t)b * Hh * Tt;

    // Q fragments (B-operand of S^T): wave's q-row = q0 + wq*16 + l15
    const int qrow = q0 + wq * 16 + l15;
    s16x8 qf[4];
#pragma unroll
    for (int ks = 0; ks < 4; ++ks)
        qf[ks] = *reinterpret_cast<const s16x8*>(
            &qb[(size_t)qrow * Hh + ks * 32 + l4 * 8]);

    f32x4 o[8];
#pragma unroll
    for (int nh = 0; nh < 8; ++nh) { f32x4 z4 = {0.f,0.f,0.f,0.f}; o[nh] = z4; }
    float mreg = -1e30f, lreg = 0.f;     // per-lane state for q-row (l15)

    // staging assignments (same as round 9)
    const int kr_s  = tid >> 2, kc_s = (tid & 3) * 4;   // K: row, 4 granules
    const int vh_s  = tid >> 1, vc_s = (tid & 1) * 4;   // V: row, 4 granules
    u16* ps = psl + wid * 16 * 80;

    for (int j = 0; j < ntiles; ++j) {
        const int kv0 = j * 64;

        // ---- cooperative staging (granule = 8 u16 = 16B; XOR-swizzled) ----
#pragma unroll
        for (int i = 0; i < 4; ++i) {
            s16x8 tk = *reinterpret_cast<const s16x8*>(
                &kb[(size_t)(kv0 + kr_s) * Hh + (kc_s + i) * 8]);
            *reinterpret_cast<s16x8*>(
                &ksl[kr_s * 128 + (((kc_s + i) * 8) ^ ((kr_s & 7) << 3))]) = tk;
        }
#pragma unroll
        for (int i = 0; i < 4; ++i) {
            s16x8 tv = *reinterpret_cast<const s16x8*>(
                &vb[(size_t)vh_s * Tt + kv0 + (vc_s + i) * 8]);
            *reinterpret_cast<s16x8*>(
                &vsl[vh_s * 64 + (((vc_s + i) * 8) ^ ((vh_s & 7) << 3))]) = tv;
        }
        __syncthreads();

        // ---- S^T = K Q^T : 8 MFMAs on this wave's kv-half ----
        f32x4 sacc[2];
#pragma unroll
        for (int nf = 0; nf < 2; ++nf) { f32x4 z4 = {0.f,0.f,0.f,0.f}; sacc[nf] = z4; }
#pragma unroll
        for (int nf = 0; nf < 2; ++nf) {
            const int kr = half * 32 + nf * 16 + l15;
#pragma unroll
            for (int ks = 0; ks < 4; ++ks) {
                s16x8 kfrag = *reinterpret_cast<const s16x8*>(
                    &ksl[kr * 128 + ((ks * 32 + l4 * 8) ^ ((kr & 7) << 3))]);
                sacc[nf] = __builtin_amdgcn_mfma_f32_16x16x32_bf16(
                    kfrag, qf[ks], sacc[nf], 0, 0, 0);
            }
        }

        // ---- mask + per-lane online softmax ----
        const bool diag = (j == ntiles - 1);
        float pv2[2][4];
#pragma unroll
        for (int nf = 0; nf < 2; ++nf)
#pragma unroll
            for (int r = 0; r < 4; ++r) {
                float s = sacc[nf][r] * kScale;
                if (diag) {
                    int kvg = kv0 + half * 32 + nf * 16 + l4 * 4 + r;
                    if (kvg > qrow) s = -1e30f;
                }
                pv2[nf][r] = s;
            }
        float mx = fmaxf(fmaxf(fmaxf(pv2[0][0], pv2[0][1]), fmaxf(pv2[0][2], pv2[0][3])),
                         fmaxf(fmaxf(pv2[1][0], pv2[1][1]), fmaxf(pv2[1][2], pv2[1][3])));
        mx = fmaxf(mx, __shfl_xor(mx, 16));
        mx = fmaxf(mx, __shfl_xor(mx, 32));
        const float mold = mreg;
        const float mnew = fmaxf(mold, mx);
        const float scl = __expf(mold - mnew);
        mreg = mnew;
        float rs = 0.f;
#pragma unroll
        for (int nf = 0; nf < 2; ++nf)
#pragma unroll
            for (int r = 0; r < 4; ++r) {
                float pp = __expf(pv2[nf][r] - mnew);
                pv2[nf][r] = pp; rs += pp;
            }
        rs += __shfl_xor(rs, 16);
        rs += __shfl_xor(rs, 32);
        lreg = lreg * scl + rs;

        if (!__all(mold == mnew)) {      // O-rescale only when max moved
            float sclr[4];
#pragma unroll
            for (int r = 0; r < 4; ++r) sclr[r] = __shfl(scl, l4 * 4 + r);
#pragma unroll
            for (int nh = 0; nh < 8; ++nh)
#pragma unroll
                for (int r = 0; r < 4; ++r) o[nh][r] *= sclr[r];
        }

        // ---- P -> per-wave LDS (row q=l15, stride 80 u16; 32 kv cols) ----
#pragma unroll
        for (int nf = 0; nf < 2; ++nf) {
            s16x4 pk4;
#pragma unroll
            for (int r = 0; r < 4; ++r) pk4[r] = (short)f2bf(pv2[nf][r]);
            *reinterpret_cast<s16x4*>(&ps[l15 * 80 + nf * 16 + l4 * 4]) = pk4;
        }
        s16x8 pa = *reinterpret_cast<const s16x8*>(&ps[l15 * 80 + l4 * 8]);

        // ---- O += P V : 8 MFMAs (V rows of this wave's kv-half) ----
#pragma unroll
        for (int nh = 0; nh < 8; ++nh) {
            const int hr = nh * 16 + l15;
            s16x8 vfrag = *reinterpret_cast<const s16x8*>(
                &vsl[hr * 64 + ((half * 32 + l4 * 8) ^ ((hr & 7) << 3))]);
            o[nh] = __builtin_amdgcn_mfma_f32_16x16x32_bf16(
                pa, vfrag, o[nh], 0, 0, 0);
        }
        __syncthreads();                 // tile consumed; safe to restage
    }

    // ---- publish partials (arena reused: staging buffers dead) ----
#pragma unroll
    for (int nh = 0; nh < 8; ++nh)
#pragma unroll
        for (int r = 0; r < 4; ++r)
            Om[((wid * 16) + l4 * 4 + r) * 132 + nh * 16 + l15] = o[nh][r];
    if (lane < 16) {
        ml2[wid * 32 + lane] = mreg;         // [wid][0][lane]
        ml2[wid * 32 + 16 + lane] = lreg;    // [wid][1][lane]
    }
    __syncthreads();

    // ---- merge 2 partials per row-group -> bf16 pm[32][136] ----
    {
        const int row = tid >> 3, ch = tid & 7;   // row 0..31, 16-col chunk
        const int rg = row >> 4, r16 = row & 15;
        const int w0 = rg * 2, w1 = rg * 2 + 1;
        float m0v = ml2[w0 * 32 + r16], m1v = ml2[w1 * 32 + r16];
        float M = fmaxf(m0v, m1v);
        float f0 = __expf(m0v - M), f1 = __expf(m1v - M);
        float L = f0 * ml2[w0 * 32 + 16 + r16] + f1 * ml2[w1 * 32 + 16 + r16];
        float inv = 1.f / L;
        union { u16 u[8]; s16x8 v; } pk0, pk1;
#pragma unroll
        for (int c = 0; c < 8; ++c) {
            float a = f0 * Om[(w0 * 16 + r16) * 132 + ch * 16 + c]
                    + f1 * Om[(w1 * 16 + r16) * 132 + ch * 16 + c];
            pk0.u[c] = f2bf(a * inv);
        }
#pragma unroll
        for (int c = 0; c < 8; ++c) {
            float a = f0 * Om[(w0 * 16 + r16) * 132 + ch * 16 + 8 + c]
                    + f1 * Om[(w1 * 16 + r16) * 132 + ch * 16 + 8 + c];
            pk1.u[c] = f2bf(a * inv);
        }
        *reinterpret_cast<s16x8*>(&pm[row * 136 + ch * 16]) = pk0.v;
        *reinterpret_cast<s16x8*>(&pm[row * 136 + ch * 16 + 8]) = pk1.v;
    }
    __syncthreads();

    // ---- fused projection: wave wid -> rows (wid>>1)*16, cols (wid&1)*64 ----
    {
        const int rg2 = (wid >> 1) * 16;
        const int cg  = (wid & 1) * 64;
        s16x8 af2[4];
#pragma unroll
        for (int ks = 0; ks < 4; ++ks)
            af2[ks] = *reinterpret_cast<const s16x8*>(
                &pm[(rg2 + l15) * 136 + ks * 32 + l4 * 8]);
#pragma unroll
        for (int ng = 0; ng < 4; ++ng) {
            const int ncol = cg + ng * 16 + l15;
            f32x4 pacc = {0.f, 0.f, 0.f, 0.f};
#pragma unroll
            for (int ks = 0; ks < 4; ++ks) {
                s16x8 wf = *reinterpret_cast<const s16x8*>(
                    &wpt[(size_t)ncol * 128 + ks * 32 + l4 * 8]);
                pacc = __builtin_amdgcn_mfma_f32_16x16x32_bf16(
                    af2[ks], wf, pacc, 0, 0, 0);
            }
            float bias = bp[ncol];
#pragma unroll
            for (int r = 0; r < 4; ++r)
                O[((size_t)(b * Tt) + q0 + rg2 + l4 * 4 + r) * Hh + ncol] =
                    pacc[r] + bias;
        }
    }
}

// ---------------------------------------------------------------------------
extern "C" void kernel_launch(void* const* d_in, const int* in_sizes, int n_in,
                              void* d_out, int out_size, void* d_ws, size_t ws_size,
                              hipStream_t stream) {
    const float* x  = (const float*)d_in[0];
    const float* Wk = (const float*)d_in[1];
    const float* Wq = (const float*)d_in[2];
    const float* Wv = (const float*)d_in[3];
    const float* Wp = (const float*)d_in[4];
    const float* bp = (const float*)d_in[5];
    float* out = (float*)d_out;

    // workspace (u16): wt 393216 | wpt 16384 | qw 2M | kw 2M | vt 2M
    u16* wtb = (u16*)d_ws;
    u16* wpt = wtb + 393216;
    u16* qw  = wpt + 16384;
    u16* kw  = qw + (size_t)Mrows * Hh;
    u16* vtb = kw + (size_t)Mrows * Hh;   // total ~13.4 MB

    convw_kernel<<<1600, 256, 0, stream>>>(Wq, Wk, Wv, Wp, wtb, wpt);
    qkv_fused<<<Mrows / 64, 512, 0, stream>>>(x, wtb, qw, kw, vtb);
    attn_kernel<<<512, 256, 0, stream>>>(qw, kw, vtb, wpt, bp, out);
}